// Round 3
// baseline (350.131 us; speedup 1.0000x reference)
//
#include <hip/hip_runtime.h>

// ---------------------------------------------------------------------------
// QalbAttention: x->(Q,K,V) proj + RoPE, per-batch temperature scale,
// causal flash attention, output projection.
// B=2, N=2048, D=1024, H=16, HD=64.  All matmuls in bf16 MFMA (16x16x32),
// fp32 accumulate. Tolerance is bf16-grade (threshold ~2.5e-2).
// ---------------------------------------------------------------------------

typedef short short8 __attribute__((ext_vector_type(8)));      // 8 bf16 (4 VGPR)
typedef float floatx4 __attribute__((ext_vector_type(4)));
typedef unsigned int uint4v __attribute__((ext_vector_type(4)));
typedef unsigned short us4 __attribute__((ext_vector_type(4)));
typedef unsigned short u16;

#define DEV __device__ __forceinline__

static const int Bb = 2, Nn = 2048, Dd = 1024, Hh = 16, HD = 64;
static const int Mm = Bb * Nn; // 4096

// ws layout (bytes)
static const size_t OFF_XB = 0;                       // x bf16   (4096x1024)  8MB
static const size_t OFF_WQ = 8388608;                 // Wq bf16  (1024x1024)  2MB
static const size_t OFF_WK = OFF_WQ + 2097152;
static const size_t OFF_WV = OFF_WK + 2097152;
static const size_t OFF_WO = OFF_WV + 2097152;
static const size_t OFF_Q  = OFF_WO + 2097152;        // (B,H,N,HD) bf16 8MB
static const size_t OFF_K  = OFF_Q + 8388608;
static const size_t OFF_V  = OFF_K + 8388608;
static const size_t OFF_AO = OFF_V + 8388608;         // (M,D) bf16 8MB
static const size_t OFF_SC = OFF_AO + 8388608;        // [0:2) inv_scale, [2:4) partials

DEV u16 f2bf(float f) {                               // RNE float->bf16
  unsigned int u = __builtin_bit_cast(unsigned int, f);
  u += 0x7fffu + ((u >> 16) & 1u);
  return (u16)(u >> 16);
}

// --------------------------- fp32 -> bf16 convert ---------------------------
__global__ void cvt_kernel(const float* __restrict__ src, u16* __restrict__ dst, int n4) {
  int i = blockIdx.x * 256 + threadIdx.x;
  if (i >= n4) return;
  float4 f = ((const float4*)src)[i];
  us4 o;
  o[0] = f2bf(f.x); o[1] = f2bf(f.y); o[2] = f2bf(f.z); o[3] = f2bf(f.w);
  ((us4*)dst)[i] = o;
}

// --------------------------- temperature scale ------------------------------
__global__ void scale_partial_kernel(const float* __restrict__ x,
                                     const float* __restrict__ cw,
                                     float* __restrict__ part) {
  int blk = blockIdx.x;            // 128 blocks: 64 per batch
  int b = blk >> 6, sl = blk & 63;
  const float4* xp = (const float4*)(x + (size_t)b * 2097152) + (size_t)sl * 8192;
  float acc = 0.f;
  for (int i = threadIdx.x; i < 8192; i += 256) {
    float4 f = xp[i];
    int d4 = (sl * 8192 + i) & 255;     // (D/4)=256
    float4 c = ((const float4*)cw)[d4];
    acc += f.x * c.x + f.y * c.y + f.z * c.z + f.w * c.w;
  }
  __shared__ float red[256];
  red[threadIdx.x] = acc;
  __syncthreads();
  for (int s = 128; s > 0; s >>= 1) {
    if (threadIdx.x < s) red[threadIdx.x] += red[threadIdx.x + s];
    __syncthreads();
  }
  if (threadIdx.x == 0) atomicAdd(&part[b], red[0]);
}

__global__ void scale_finalize_kernel(const float* __restrict__ part,
                                      const float* __restrict__ cb,
                                      const float* __restrict__ alpha,
                                      const float* __restrict__ tb,
                                      const int* __restrict__ tstep,
                                      float* __restrict__ out) {
  int b = threadIdx.x;
  if (b >= Bb) return;
  float sm = part[b] * (1.0f / 2048.0f) + cb[0];
  float cx = 1.0f / (1.0f + expf(-sm));
  float Te = (fabsf(tb[0]) + 1.0f) * (0.5f + cx);
  float psi = 1.0f + alpha[0] * sinf(6.283185307179586f * (float)tstep[0] / Te);
  out[b] = 1.0f / (8.0f * psi);        // scores get multiplied by this
}

// --------------------------- QKV GEMM + RoPE --------------------------------
// C[m,e] = sum_k A[m,k]*W[e,k]; 128x128 tile, BK=32, 4 waves 2x2, 4x4 frags.
__global__ __launch_bounds__(256) void gemm_qkv_kernel(
    const u16* __restrict__ xb, const u16* __restrict__ wq, const u16* __restrict__ wk,
    const u16* __restrict__ wv, u16* __restrict__ q, u16* __restrict__ k,
    u16* __restrict__ v) {
  const int tm = blockIdx.x, tn = blockIdx.y, which = blockIdx.z;
  const u16* W = (which == 0) ? wq : (which == 1) ? wk : wv;
  u16* dst = (which == 0) ? q : (which == 1) ? k : v;

  __shared__ __align__(16) u16 As[128 * 32];
  __shared__ __align__(16) u16 Bs[128 * 32];

  const int t = threadIdx.x, lane = t & 63, w = t >> 6;
  const int wm = w >> 1, wn = w & 1, lg = lane >> 4, lr = lane & 15;

  floatx4 acc[4][4];
#pragma unroll
  for (int i = 0; i < 4; i++)
#pragma unroll
    for (int j = 0; j < 4; j++) acc[i][j] = (floatx4){0.f, 0.f, 0.f, 0.f};

  const int rowA = tm * 128, rowB = tn * 128;
  for (int kt = 0; kt < 32; ++kt) {
#pragma unroll
    for (int s = 0; s < 2; s++) {
      int c = t + s * 256;
      int r = c >> 2, kc = c & 3;     // 32 bf16/row = 4 x 16B chunks
      *(uint4v*)(As + r * 32 + kc * 8) =
          *(const uint4v*)(xb + (size_t)(rowA + r) * 1024 + kt * 32 + kc * 8);
      *(uint4v*)(Bs + r * 32 + kc * 8) =
          *(const uint4v*)(W + (size_t)(rowB + r) * 1024 + kt * 32 + kc * 8);
    }
    __syncthreads();
    short8 af[4], bw[4];
#pragma unroll
    for (int i = 0; i < 4; i++)
      af[i] = *(const short8*)(As + (wm * 64 + i * 16 + lr) * 32 + lg * 8);
#pragma unroll
    for (int j = 0; j < 4; j++)
      bw[j] = *(const short8*)(Bs + (wn * 64 + j * 16 + lr) * 32 + lg * 8);
#pragma unroll
    for (int i = 0; i < 4; i++)
#pragma unroll
      for (int j = 0; j < 4; j++)
        acc[i][j] = __builtin_amdgcn_mfma_f32_16x16x32_bf16(af[i], bw[j], acc[i][j], 0, 0, 0);
    __syncthreads();
  }

  const int rowbase = tm * 128 + wm * 64, colbase = tn * 128 + wn * 64;
  if (which <= 1) {
    // RoPE epilogue: partner hd±32 is frag j±2 in the SAME lane, same angle.
#pragma unroll
    for (int i = 0; i < 4; i++)
#pragma unroll
      for (int ii = 0; ii < 4; ii++) {
        int gm = rowbase + i * 16 + lg * 4 + ii;
        int pos = gm & 2047, bb = gm >> 11;
#pragma unroll
        for (int jp = 0; jp < 2; jp++) {
          int hd2 = jp * 16 + lr;                           // 0..31
          float ang = (float)pos * exp2f(-(float)hd2 * 0.41524101186092030f);
          float sv, cv;
          sincosf(ang, &sv, &cv);
          float a0 = acc[i][jp][ii], a1 = acc[i][jp + 2][ii];
          int e0 = colbase + jp * 16 + lr;
          int hh = e0 >> 6;
          size_t base = (((size_t)bb * 16 + hh) * 2048 + pos) * 64;
          dst[base + hd2]      = f2bf(a0 * cv - a1 * sv);   // hd < 32
          dst[base + hd2 + 32] = f2bf(a1 * cv + a0 * sv);   // hd >= 32
        }
      }
  } else {
#pragma unroll
    for (int i = 0; i < 4; i++)
#pragma unroll
      for (int ii = 0; ii < 4; ii++) {
        int gm = rowbase + i * 16 + lg * 4 + ii;
        int pos = gm & 2047, bb = gm >> 11;
#pragma unroll
        for (int j = 0; j < 4; j++) {
          int ge = colbase + j * 16 + lr;
          int hh = ge >> 6, hd = ge & 63;
          dst[(((size_t)bb * 16 + hh) * 2048 + pos) * 64 + hd] = f2bf(acc[i][j][ii]);
        }
      }
  }
}

// --------------------------- flash attention --------------------------------
// block = (qt, h, b); 4 waves; QBLK=KBLK=64; online softmax; causal.
// LDS tiles XOR-swizzled at 16B granularity: chunk ^= (row&7).
__global__ __launch_bounds__(256) void attn_kernel(
    const u16* __restrict__ q, const u16* __restrict__ k, const u16* __restrict__ v,
    u16* __restrict__ ao, const float* __restrict__ scale_ws) {
  const int qt = blockIdx.x, h = blockIdx.y, b = blockIdx.z;
  const float isc = scale_ws[b];

  __shared__ __align__(16) u16 Qs[64 * 64];
  __shared__ __align__(16) u16 Ks[64 * 64];
  __shared__ __align__(16) u16 Vt[64 * 64];   // transposed: [d][c]
  __shared__ __align__(16) u16 Ps[64 * 64];

  const int t = threadIdx.x, lane = t & 63, w = t >> 6, lg = lane >> 4, lr = lane & 15;
  const size_t hb = ((size_t)(b * 16 + h)) * 2048 * 64;

#pragma unroll
  for (int s = 0; s < 2; s++) {               // stage Q once
    int c = t + s * 256, r = c >> 3, kc = c & 7;
    *(uint4v*)(Qs + r * 64 + ((kc ^ (r & 7)) * 8)) =
        *(const uint4v*)(q + hb + (size_t)(qt * 64 + r) * 64 + kc * 8);
  }

  floatx4 o[4];
#pragma unroll
  for (int n = 0; n < 4; n++) o[n] = (floatx4){0.f, 0.f, 0.f, 0.f};
  float mrow[4] = {-__builtin_inff(), -__builtin_inff(), -__builtin_inff(), -__builtin_inff()};
  float lrow[4] = {0.f, 0.f, 0.f, 0.f};

  const int vd = t & 63, vcb = (t >> 6) * 16;
  const float LOG2E = 1.4426950408889634f;

  for (int kt = 0; kt <= qt; ++kt) {
    // stage K rows [c][d]
#pragma unroll
    for (int s = 0; s < 2; s++) {
      int c = t + s * 256, r = c >> 3, kc = c & 7;
      *(uint4v*)(Ks + r * 64 + ((kc ^ (r & 7)) * 8)) =
          *(const uint4v*)(k + hb + (size_t)(kt * 64 + r) * 64 + kc * 8);
    }
    // stage V transposed: thread owns col d=vd, 4 c's per write
#pragma unroll
    for (int it = 0; it < 4; ++it) {
      int c0 = vcb + it * 4;
      us4 pack;
#pragma unroll
      for (int i2 = 0; i2 < 4; i2++) pack[i2] = v[hb + (size_t)(kt * 64 + c0 + i2) * 64 + vd];
      *(us4*)(Vt + vd * 64 + (((c0 >> 3) ^ (vd & 7)) * 8) + (c0 & 7)) = pack;
    }
    __syncthreads();

    // S = Q K^T (wave w owns S rows 16w..16w+15)
    int qrow = 16 * w + lr;
    short8 aq0 = *(const short8*)(Qs + qrow * 64 + (((0 + lg) ^ (qrow & 7)) * 8));
    short8 aq1 = *(const short8*)(Qs + qrow * 64 + (((4 + lg) ^ (qrow & 7)) * 8));
    float sf[4][4];
#pragma unroll
    for (int n = 0; n < 4; n++) {
      int krow = 16 * n + lr;
      short8 b0 = *(const short8*)(Ks + krow * 64 + (((0 + lg) ^ (krow & 7)) * 8));
      short8 b1 = *(const short8*)(Ks + krow * 64 + (((4 + lg) ^ (krow & 7)) * 8));
      floatx4 sacc = (floatx4){0.f, 0.f, 0.f, 0.f};
      sacc = __builtin_amdgcn_mfma_f32_16x16x32_bf16(aq0, b0, sacc, 0, 0, 0);
      sacc = __builtin_amdgcn_mfma_f32_16x16x32_bf16(aq1, b1, sacc, 0, 0, 0);
#pragma unroll
      for (int ii = 0; ii < 4; ii++) {
        int colg = kt * 64 + n * 16 + lr;
        int rowg = qt * 64 + 16 * w + lg * 4 + ii;
        sf[n][ii] = (colg > rowg) ? -__builtin_inff() : sacc[ii] * isc;
      }
    }

    // online softmax over rows lg*4+ii (16 lanes of this lg-group share rows)
    float resc[4];
#pragma unroll
    for (int ii = 0; ii < 4; ii++) {
      float mx = fmaxf(fmaxf(sf[0][ii], sf[1][ii]), fmaxf(sf[2][ii], sf[3][ii]));
      mx = fmaxf(mx, __shfl_xor(mx, 1, 64));
      mx = fmaxf(mx, __shfl_xor(mx, 2, 64));
      mx = fmaxf(mx, __shfl_xor(mx, 4, 64));
      mx = fmaxf(mx, __shfl_xor(mx, 8, 64));
      float mnew = fmaxf(mrow[ii], mx);
      resc[ii] = exp2f((mrow[ii] - mnew) * LOG2E);
      mrow[ii] = mnew;
    }
    float ps[4][4], psum[4] = {0.f, 0.f, 0.f, 0.f};
#pragma unroll
    for (int n = 0; n < 4; n++)
#pragma unroll
      for (int ii = 0; ii < 4; ii++) {
        float p = exp2f((sf[n][ii] - mrow[ii]) * LOG2E);
        ps[n][ii] = p;
        psum[ii] += p;
      }
#pragma unroll
    for (int ii = 0; ii < 4; ii++) {
      float su = psum[ii];
      su += __shfl_xor(su, 1, 64);
      su += __shfl_xor(su, 2, 64);
      su += __shfl_xor(su, 4, 64);
      su += __shfl_xor(su, 8, 64);
      lrow[ii] = lrow[ii] * resc[ii] + su;
    }
#pragma unroll
    for (int n = 0; n < 4; n++)
#pragma unroll
      for (int ii = 0; ii < 4; ii++) o[n][ii] *= resc[ii];

    // P -> LDS (wave-private rows; same-wave RAW handled by lgkmcnt)
#pragma unroll
    for (int n = 0; n < 4; n++)
#pragma unroll
      for (int ii = 0; ii < 4; ii++) {
        int pr = 16 * w + lg * 4 + ii;
        int pc = n * 16 + lr;
        Ps[pr * 64 + (((pc >> 3) ^ (pr & 7)) * 8) + (pc & 7)] = f2bf(ps[n][ii]);
      }

    // O += P V
#pragma unroll
    for (int kk = 0; kk < 2; kk++) {
      int prow = 16 * w + lr;
      short8 ap = *(const short8*)(Ps + prow * 64 + (((kk * 4 + lg) ^ (prow & 7)) * 8));
#pragma unroll
      for (int n = 0; n < 4; n++) {
        int vrow = 16 * n + lr;
        short8 bv = *(const short8*)(Vt + vrow * 64 + (((kk * 4 + lg) ^ (vrow & 7)) * 8));
        o[n] = __builtin_amdgcn_mfma_f32_16x16x32_bf16(ap, bv, o[n], 0, 0, 0);
      }
    }
    __syncthreads();
  }

#pragma unroll
  for (int ii = 0; ii < 4; ii++) {
    float invl = 1.0f / lrow[ii];
    int rowg = qt * 64 + 16 * w + lg * 4 + ii;
    size_t rb = ((size_t)(b * 2048 + rowg)) * 1024 + h * 64;
#pragma unroll
    for (int n = 0; n < 4; n++) ao[rb + n * 16 + lr] = f2bf(o[n][ii] * invl);
  }
}

// --------------------------- output projection ------------------------------
__global__ __launch_bounds__(256) void gemm_out_kernel(const u16* __restrict__ ab,
                                                       const u16* __restrict__ wo,
                                                       float* __restrict__ out) {
  const int tm = blockIdx.x, tn = blockIdx.y;
  __shared__ __align__(16) u16 As[128 * 32];
  __shared__ __align__(16) u16 Bs[128 * 32];

  const int t = threadIdx.x, lane = t & 63, w = t >> 6;
  const int wm = w >> 1, wn = w & 1, lg = lane >> 4, lr = lane & 15;

  floatx4 acc[4][4];
#pragma unroll
  for (int i = 0; i < 4; i++)
#pragma unroll
    for (int j = 0; j < 4; j++) acc[i][j] = (floatx4){0.f, 0.f, 0.f, 0.f};

  const int rowA = tm * 128, rowB = tn * 128;
  for (int kt = 0; kt < 32; ++kt) {
#pragma unroll
    for (int s = 0; s < 2; s++) {
      int c = t + s * 256;
      int r = c >> 2, kc = c & 3;
      *(uint4v*)(As + r * 32 + kc * 8) =
          *(const uint4v*)(ab + (size_t)(rowA + r) * 1024 + kt * 32 + kc * 8);
      *(uint4v*)(Bs + r * 32 + kc * 8) =
          *(const uint4v*)(wo + (size_t)(rowB + r) * 1024 + kt * 32 + kc * 8);
    }
    __syncthreads();
    short8 af[4], bw[4];
#pragma unroll
    for (int i = 0; i < 4; i++)
      af[i] = *(const short8*)(As + (wm * 64 + i * 16 + lr) * 32 + lg * 8);
#pragma unroll
    for (int j = 0; j < 4; j++)
      bw[j] = *(const short8*)(Bs + (wn * 64 + j * 16 + lr) * 32 + lg * 8);
#pragma unroll
    for (int i = 0; i < 4; i++)
#pragma unroll
      for (int j = 0; j < 4; j++)
        acc[i][j] = __builtin_amdgcn_mfma_f32_16x16x32_bf16(af[i], bw[j], acc[i][j], 0, 0, 0);
    __syncthreads();
  }

  const int rowbase = tm * 128 + wm * 64, colbase = tn * 128 + wn * 64;
#pragma unroll
  for (int i = 0; i < 4; i++)
#pragma unroll
    for (int ii = 0; ii < 4; ii++) {
      int gm = rowbase + i * 16 + lg * 4 + ii;
#pragma unroll
      for (int j = 0; j < 4; j++) {
        int ge = colbase + j * 16 + lr;
        out[(size_t)gm * 1024 + ge] = acc[i][j][ii];
      }
    }
}

// ---------------------------------------------------------------------------
extern "C" void kernel_launch(void* const* d_in, const int* in_sizes, int n_in,
                              void* d_out, int out_size, void* d_ws, size_t ws_size,
                              hipStream_t stream) {
  const float* x     = (const float*)d_in[0];
  const float* Wq    = (const float*)d_in[1];
  const float* Wk    = (const float*)d_in[2];
  const float* Wv    = (const float*)d_in[3];
  const float* Wo    = (const float*)d_in[4];
  const float* alpha = (const float*)d_in[5];
  const float* Tb    = (const float*)d_in[6];
  const float* cw    = (const float*)d_in[7];
  const float* cb    = (const float*)d_in[8];
  const int*   tstep = (const int*)d_in[11];

  char* ws = (char*)d_ws;
  u16* xb  = (u16*)(ws + OFF_XB);
  u16* wqb = (u16*)(ws + OFF_WQ);
  u16* wkb = (u16*)(ws + OFF_WK);
  u16* wvb = (u16*)(ws + OFF_WV);
  u16* wob = (u16*)(ws + OFF_WO);
  u16* qb  = (u16*)(ws + OFF_Q);
  u16* kb  = (u16*)(ws + OFF_K);
  u16* vb  = (u16*)(ws + OFF_V);
  u16* aob = (u16*)(ws + OFF_AO);
  float* sc = (float*)(ws + OFF_SC);        // [0:2) inv_scale, [2:4) partials

  // bf16 converts
  cvt_kernel<<<4096, 256, 0, stream>>>(x, xb, 1048576);
  cvt_kernel<<<1024, 256, 0, stream>>>(Wq, wqb, 262144);
  cvt_kernel<<<1024, 256, 0, stream>>>(Wk, wkb, 262144);
  cvt_kernel<<<1024, 256, 0, stream>>>(Wv, wvb, 262144);
  cvt_kernel<<<1024, 256, 0, stream>>>(Wo, wob, 262144);

  // temperature scale
  hipMemsetAsync(sc + 2, 0, 2 * sizeof(float), stream);
  scale_partial_kernel<<<128, 256, 0, stream>>>(x, cw, sc + 2);
  scale_finalize_kernel<<<1, 64, 0, stream>>>(sc + 2, cb, alpha, Tb, tstep, sc);

  // QKV projection + RoPE
  gemm_qkv_kernel<<<dim3(32, 8, 3), 256, 0, stream>>>(xb, wqb, wkb, wvb, qb, kb, vb);

  // causal flash attention
  attn_kernel<<<dim3(32, 16, 2), 256, 0, stream>>>(qb, kb, vb, aob, sc);

  // output projection
  gemm_out_kernel<<<dim3(32, 8), 256, 0, stream>>>(aob, wob, (float*)d_out);
}